// Round 15
// baseline (423.101 us; speedup 1.0000x reference)
//
#include <hip/hip_runtime.h>
#include <math.h>

constexpr int NB = 8;
constexpr int NC = 256;
constexpr int NCR = 64;
constexpr int NH = 160;
constexpr int NW = 160;
constexpr int NHW = NH * NW;           // 25600
constexpr float KEPS = 1e-4f;

constexpr int TW = 32;                 // tile width (k_logits)
constexpr int TH = 8;                  // tile height (k_logits)

// K0: transpose rw[d][c] -> rwT[c][d]; block 0 also zeroes pooledsum
__global__ __launch_bounds__(256) void k_tr(const float* __restrict__ rw,
                                            float* __restrict__ rwT,
                                            float* __restrict__ pooledsum) {
    const int i = blockIdx.x * 256 + threadIdx.x;    // over 16384
    const int d = i >> 8, c = i & 255;
    rwT[c * NCR + d] = rw[i];
    if (blockIdx.x == 0) {
        pooledsum[threadIdx.x] = 0.f;
        pooledsum[256 + threadIdx.x] = 0.f;
    }
}

// 2 px (u0,u1) x 1 d (scalar w) accumulate into float2
#define FMA2(A, W) A.x = fmaf(u0, (W), A.x); A.y = fmaf(u1, (W), A.y);

// K1: y[b,d,p] = sum_c x[b,c,p] * rwT[c][d]. Canonical staged structure:
// block = 128 px x ALL 64 d (4 waves x 16 d). x-tile staged in LDS
// (16 channels x 128 px = 8 KB, double-buffered): x crosses global ONCE
// per block (every previous round: 4x, once per wave). T14 async split:
// issue next-buffer loads -> consume current -> ds_write late -> barrier.
// Weights on scalar path (wave-uniform). Thread = 2px x 16d = 32 named accs.
// Grid = 200x8 = 1600 blocks (~6 blocks/CU, ~24 waves/CU TLP).
__global__ __launch_bounds__(256, 1) void k_reduce(const float* __restrict__ x,
                                                   const float* __restrict__ rwT,
                                                   float* __restrict__ y,
                                                   float* __restrict__ pooledsum) {
    __shared__ float xs[2][16 * 128];              // 16 KB total
    const int t = threadIdx.x;
    const int L = t & 63;
    const int wv = __builtin_amdgcn_readfirstlane(t >> 6);   // 0..3
    const int b = blockIdx.y;
    const int P0 = blockIdx.x * 128;
    const int dbase = wv * 16;

    const float* __restrict__ wp = rwT + dbase;    // wave-uniform
    const float* __restrict__ xb = x + (size_t)b * NC * NHW + P0;

    // slot decomposition for staging: 512 float4-slots over 16 ch x 32 words
    const int ch0 = t >> 5,        pw0 = t & 31;          // slot t
    const int ch1 = (256 + t) >> 5, pw1 = t & 31;         // slot 256+t

    {   // prologue: stage channels 0..15 into buffer 0
        const float4 v0 = *reinterpret_cast<const float4*>(xb + (size_t)ch0 * NHW + pw0 * 4);
        const float4 v1 = *reinterpret_cast<const float4*>(xb + (size_t)ch1 * NHW + pw1 * 4);
        float* d0 = &xs[0][ch0 * 128 + pw0 * 4];
        float* d1 = &xs[0][ch1 * 128 + pw1 * 4];
        d0[0] = v0.x; d0[1] = v0.y; d0[2] = v0.z; d0[3] = v0.w;
        d1[0] = v1.x; d1[1] = v1.y; d1[2] = v1.z; d1[3] = v1.w;
    }
    __syncthreads();

    float2 A0{0,0},  A1{0,0},  A2{0,0},  A3{0,0};
    float2 A4{0,0},  A5{0,0},  A6{0,0},  A7{0,0};
    float2 A8{0,0},  A9{0,0},  A10{0,0}, A11{0,0};
    float2 A12{0,0}, A13{0,0}, A14{0,0}, A15{0,0};

    int cur = 0;
#pragma unroll 1
    for (int cs = 0; cs < NC; cs += 16) {
        const bool more = (cs + 16 < NC);
        float4 g0, g1;
        if (more) {    // T14: issue loads EARLY (complete during consume)
            g0 = *reinterpret_cast<const float4*>(xb + (size_t)(cs + 16 + ch0) * NHW + pw0 * 4);
            g1 = *reinterpret_cast<const float4*>(xb + (size_t)(cs + 16 + ch1) * NHW + pw1 * 4);
        }
        const float* xbuf = &xs[cur][0];
#pragma unroll
        for (int j = 0; j < 16; ++j) {
            const int c = cs + j;
            const float u0 = xbuf[j * 128 + L];
            const float u1 = xbuf[j * 128 + 64 + L];
            const float4 w0 = *reinterpret_cast<const float4*>(wp + (size_t)c * NCR);
            const float4 w1 = *reinterpret_cast<const float4*>(wp + (size_t)c * NCR + 4);
            const float4 w2 = *reinterpret_cast<const float4*>(wp + (size_t)c * NCR + 8);
            const float4 w3 = *reinterpret_cast<const float4*>(wp + (size_t)c * NCR + 12);
            FMA2(A0,  w0.x); FMA2(A1,  w0.y); FMA2(A2,  w0.z); FMA2(A3,  w0.w);
            FMA2(A4,  w1.x); FMA2(A5,  w1.y); FMA2(A6,  w1.z); FMA2(A7,  w1.w);
            FMA2(A8,  w2.x); FMA2(A9,  w2.y); FMA2(A10, w2.z); FMA2(A11, w2.w);
            FMA2(A12, w3.x); FMA2(A13, w3.y); FMA2(A14, w3.z); FMA2(A15, w3.w);
        }
        if (more) {    // T14: write LATE into the other buffer
            float* d0 = &xs[cur ^ 1][ch0 * 128 + pw0 * 4];
            float* d1 = &xs[cur ^ 1][ch1 * 128 + pw1 * 4];
            d0[0] = g0.x; d0[1] = g0.y; d0[2] = g0.z; d0[3] = g0.w;
            d1[0] = g1.x; d1[1] = g1.y; d1[2] = g1.z; d1[3] = g1.w;
        }
        __syncthreads();
        cur ^= 1;
    }

    float* yb = y + ((size_t)b * NCR + dbase) * NHW + P0 + L;
#define YST(K, A) \
    yb[(size_t)(K) * NHW] = A.x; yb[(size_t)(K) * NHW + 64] = A.y;
    YST(0, A0);   YST(1, A1);   YST(2, A2);   YST(3, A3);
    YST(4, A4);   YST(5, A5);   YST(6, A6);   YST(7, A7);
    YST(8, A8);   YST(9, A9);   YST(10, A10); YST(11, A11);
    YST(12, A12); YST(13, A13); YST(14, A14); YST(15, A15);
#undef YST

    float* ps = pooledsum + b * NCR + dbase;
#define PRED(K, A) { \
    float s_ = A.x + A.y; \
    _Pragma("unroll") \
    for (int o_ = 32; o_ > 0; o_ >>= 1) s_ += __shfl_down(s_, o_, 64); \
    if (L == 0) atomicAdd(&ps[K], s_); }
    PRED(0, A0);   PRED(1, A1);   PRED(2, A2);   PRED(3, A3);
    PRED(4, A4);   PRED(5, A5);   PRED(6, A6);   PRED(7, A7);
    PRED(8, A8);   PRED(9, A9);   PRED(10, A10); PRED(11, A11);
    PRED(12, A12); PRED(13, A13); PRED(14, A14); PRED(15, A15);
#undef PRED
}

// K2: gamma[b,d] = sigmoid(relu(mean@w1^T+b1)@w2^T+b2); pooledsum -> mean
__global__ __launch_bounds__(512) void k_gate(const float* __restrict__ pooledsum,
                                              const float* __restrict__ w1,
                                              const float* __restrict__ b1,
                                              const float* __restrict__ w2,
                                              const float* __restrict__ b2,
                                              float* __restrict__ gamma) {
    __shared__ float hsh[NB][16];
    const int t = threadIdx.x;
    constexpr float inv = 1.f / (float)NHW;
    if (t < NB * 16) {
        const int b = t / 16, j = t % 16;
        float s = b1[j];
        for (int d = 0; d < NCR; ++d)
            s = fmaf(pooledsum[b * NCR + d] * inv, w1[j * NCR + d], s);
        hsh[b][j] = fmaxf(s, 0.f);
    }
    __syncthreads();
    const int b = t / NCR, d = t % NCR;
    float s = b2[d];
#pragma unroll
    for (int j = 0; j < 16; ++j) s = fmaf(hsh[b][j], w2[d * 16 + j], s);
    gamma[t] = 1.f / (1.f + expf(-s));
}

// K3a: per (b, 32x8 tile): stencil on y -> kappa -> logits -> m = 1+sigmoid
__global__ __launch_bounds__(256) void k_logits(const float* __restrict__ y,
                                                const float* __restrict__ gamma,
                                                const float* __restrict__ fw,
                                                float* __restrict__ m) {
    __shared__ float tile[TH + 2][TW + 2];           // 10 x 34
    __shared__ float coef[NCR];

    const int b = blockIdx.z;
    const int w0 = blockIdx.x * TW, h0 = blockIdx.y * TH;
    const int t = threadIdx.x;
    const int tx = t % TW, ty = t / TW;

    if (t < NCR) coef[t] = fw[t] + gamma[b * NCR + t] * fw[NCR + t];
    __syncthreads();

    const float* yb = y + (size_t)b * NCR * NHW;
    float logit = 0.f;

    for (int c = 0; c < NCR; ++c) {
        const float* yc = yb + (size_t)c * NHW;
        for (int i = t; i < (TH + 2) * (TW + 2); i += 256) {
            const int iy = i / (TW + 2), ix = i % (TW + 2);
            const int gh = h0 + iy - 1, gw = w0 + ix - 1;
            float v = 0.f;
            if (gh >= 0 && gh < NH && gw >= 0 && gw < NW) v = yc[gh * NW + gw];
            tile[iy][ix] = v;
        }
        __syncthreads();

        const float a00 = tile[ty][tx],     a01 = tile[ty][tx + 1],     a02 = tile[ty][tx + 2];
        const float a10 = tile[ty + 1][tx], a11 = tile[ty + 1][tx + 1], a12 = tile[ty + 1][tx + 2];
        const float a20 = tile[ty + 2][tx], a21 = tile[ty + 2][tx + 1], a22 = tile[ty + 2][tx + 2];

        const float mu = (a00 + a01 + a02 + a10 + a11 + a12 + a20 + a21 + a22) * (1.f / 9.f);
        const float gx = (a00 - a02 + 2.f * (a10 - a12) + a20 - a22) * 0.125f;
        const float gy = (a00 + 2.f * a01 + a02 - a20 - 2.f * a21 - a22) * 0.125f;
        const float kappa = 1.f - fabsf(a11 - mu) / (fabsf(gx) + fabsf(gy) + KEPS);
        logit = fmaf(kappa, coef[c], logit);
        __syncthreads();
    }

    const float a = 1.f / (1.f + expf(-logit));
    m[(size_t)b * NHW + (h0 + ty) * NW + (w0 + tx)] = 1.f + a;
}

// K3b: pure stream out = x * m. Block: 256 thr over 1024 px; 4 channels each.
__global__ __launch_bounds__(256) void k_mul(const float* __restrict__ x,
                                             const float* __restrict__ m,
                                             float* __restrict__ out) {
    const int b = blockIdx.z;
    const int c0 = blockIdx.y * 4;
    const int p = blockIdx.x * 1024 + threadIdx.x * 4;

    const float4 mv = *reinterpret_cast<const float4*>(m + (size_t)b * NHW + p);
    const size_t base = (size_t)b * NC * NHW + (size_t)c0 * NHW + p;
    const float* xp = x + base;
    float* op = out + base;

#pragma unroll
    for (int cc = 0; cc < 4; ++cc) {
        const float4 v = *reinterpret_cast<const float4*>(xp + (size_t)cc * NHW);
        float4 r;
        r.x = v.x * mv.x; r.y = v.y * mv.y; r.z = v.z * mv.z; r.w = v.w * mv.w;
        *reinterpret_cast<float4*>(op + (size_t)cc * NHW) = r;
    }
}

extern "C" void kernel_launch(void* const* d_in, const int* in_sizes, int n_in,
                              void* d_out, int out_size, void* d_ws, size_t ws_size,
                              hipStream_t stream) {
    const float* x  = (const float*)d_in[0];
    const float* rw = (const float*)d_in[1];
    const float* w1 = (const float*)d_in[2];
    const float* b1 = (const float*)d_in[3];
    const float* w2 = (const float*)d_in[4];
    const float* b2 = (const float*)d_in[5];
    const float* fw = (const float*)d_in[6];
    float* out = (float*)d_out;

    float* y      = (float*)d_ws;                       // 13,107,200 floats
    float* pooled = y + (size_t)NB * NCR * NHW;         // 512 floats (sums)
    float* gamma  = pooled + NB * NCR;                  // 512 floats
    float* rwT    = gamma + NB * NCR;                   // 16384 floats
    float* m      = rwT + NC * NCR;                     // 204800 floats

    k_tr<<<dim3(64), 256, 0, stream>>>(rw, rwT, pooled);
    k_reduce<<<dim3(NHW / 128, NB), 256, 0, stream>>>(x, rwT, y, pooled);
    k_gate<<<dim3(1), 512, 0, stream>>>(pooled, w1, b1, w2, b2, gamma);
    k_logits<<<dim3(NW / TW, NH / TH, NB), 256, 0, stream>>>(y, gamma, fw, m);
    k_mul<<<dim3(NHW / 1024, NC / 4, NB), 256, 0, stream>>>(x, m, out);
}

// Round 16
// 369.504 us; speedup vs baseline: 1.1451x; 1.1451x over previous
//
#include <hip/hip_runtime.h>
#include <math.h>

constexpr int NB = 8;
constexpr int NC = 256;
constexpr int NCR = 64;
constexpr int NH = 160;
constexpr int NW = 160;
constexpr int NHW = NH * NW;           // 25600
constexpr float KEPS = 1e-4f;

constexpr int TW = 32;                 // tile width (k_logits)
constexpr int TH = 8;                  // tile height (k_logits)

// K0: transpose rw[d][c] -> rwT[c][d]; block 0 also zeroes pooledsum
__global__ __launch_bounds__(256) void k_tr(const float* __restrict__ rw,
                                            float* __restrict__ rwT,
                                            float* __restrict__ pooledsum) {
    const int i = blockIdx.x * 256 + threadIdx.x;    // over 16384
    const int d = i >> 8, c = i & 255;
    rwT[c * NCR + d] = rw[i];
    if (blockIdx.x == 0) {
        pooledsum[threadIdx.x] = 0.f;
        pooledsum[256 + threadIdx.x] = 0.f;
    }
}

#define FMA4(A, X, W) \
    A.x = fmaf((X).x, (W), A.x); A.y = fmaf((X).y, (W), A.y); \
    A.z = fmaf((X).z, (W), A.z); A.w = fmaf((X).w, (W), A.w)

// K1: partial y over a 128-channel half. EXACT R6 thread shape (8px x 16d,
// 32 named float4 accs, LDS-broadcast weights, unroll-4 load-use inner loop)
// -- single delta vs R6: c-split per block. Grid 50x8x2 = 800 blocks
// (R6: 400 = 1.56 blocks/CU, half the CUs underfilled; now ~3 blocks/CU
// resident with tail 32). Weights 32 KB staged ONCE, zero mid-loop barriers.
// Half 0 -> y0 (ws); half 1 -> y1 (d_out scratch; k_mul overwrites later).
__global__ __launch_bounds__(256, 1) void k_reduce(const float* __restrict__ x,
                                                   const float* __restrict__ rwT,
                                                   float* __restrict__ y0,
                                                   float* __restrict__ y1,
                                                   float* __restrict__ pooledsum) {
    __shared__ float wlds[128 * NCR];                // 32768 B: [c-of-half][64 d]
    const int t = threadIdx.x;
    const int lane = t & 63;
    const int dg = t >> 6;                           // wave id = d-group 0..3
    const int half = blockIdx.z;
    const int b = blockIdx.y;
    const int p0 = blockIdx.x * 512 + lane * 4;      // px group0; group1 = +256
    const int cbase = half * 128;

    {   // stage this half's weights: 2048 float4, 8 per thread
        const float4* src = reinterpret_cast<const float4*>(rwT + (size_t)cbase * NCR);
        float4* dst = reinterpret_cast<float4*>(wlds);
#pragma unroll
        for (int i = 0; i < 8; ++i) dst[i * 256 + t] = src[i * 256 + t];
    }
    __syncthreads();

    const float* xb = x + (size_t)b * NC * NHW + (size_t)cbase * NHW + p0;

    float4 Aa[16], Ab[16];
#pragma unroll
    for (int d = 0; d < 16; ++d) { Aa[d] = float4{0,0,0,0}; Ab[d] = float4{0,0,0,0}; }

#pragma unroll 4
    for (int c = 0; c < 128; ++c) {
        const float4 u = *reinterpret_cast<const float4*>(xb + (size_t)c * NHW);
        const float4 v = *reinterpret_cast<const float4*>(xb + (size_t)c * NHW + 256);
        const float4* wr = reinterpret_cast<const float4*>(wlds + c * NCR + dg * 16);
        const float4 w0 = wr[0], w1 = wr[1], w2 = wr[2], w3 = wr[3];
        FMA4(Aa[0],  u, w0.x); FMA4(Ab[0],  v, w0.x);
        FMA4(Aa[1],  u, w0.y); FMA4(Ab[1],  v, w0.y);
        FMA4(Aa[2],  u, w0.z); FMA4(Ab[2],  v, w0.z);
        FMA4(Aa[3],  u, w0.w); FMA4(Ab[3],  v, w0.w);
        FMA4(Aa[4],  u, w1.x); FMA4(Ab[4],  v, w1.x);
        FMA4(Aa[5],  u, w1.y); FMA4(Ab[5],  v, w1.y);
        FMA4(Aa[6],  u, w1.z); FMA4(Ab[6],  v, w1.z);
        FMA4(Aa[7],  u, w1.w); FMA4(Ab[7],  v, w1.w);
        FMA4(Aa[8],  u, w2.x); FMA4(Ab[8],  v, w2.x);
        FMA4(Aa[9],  u, w2.y); FMA4(Ab[9],  v, w2.y);
        FMA4(Aa[10], u, w2.z); FMA4(Ab[10], v, w2.z);
        FMA4(Aa[11], u, w2.w); FMA4(Ab[11], v, w2.w);
        FMA4(Aa[12], u, w3.x); FMA4(Ab[12], v, w3.x);
        FMA4(Aa[13], u, w3.y); FMA4(Ab[13], v, w3.y);
        FMA4(Aa[14], u, w3.z); FMA4(Ab[14], v, w3.z);
        FMA4(Aa[15], u, w3.w); FMA4(Ab[15], v, w3.w);
    }

    float* yb = (half ? y1 : y0) + ((size_t)b * NCR + (size_t)(dg * 16)) * NHW + p0;
#pragma unroll
    for (int d = 0; d < 16; ++d) {
        *reinterpret_cast<float4*>(yb + (size_t)d * NHW) = Aa[d];
        *reinterpret_cast<float4*>(yb + (size_t)d * NHW + 256) = Ab[d];
    }

    float* ps = pooledsum + b * NCR + dg * 16;
#pragma unroll
    for (int d = 0; d < 16; ++d) {
        float s = Aa[d].x + Aa[d].y + Aa[d].z + Aa[d].w
                + Ab[d].x + Ab[d].y + Ab[d].z + Ab[d].w;
#pragma unroll
        for (int o = 32; o > 0; o >>= 1) s += __shfl_down(s, o, 64);
        if (lane == 0) atomicAdd(&ps[d], s);
    }
}

// K2: gamma[b,d] = sigmoid(relu(mean@w1^T+b1)@w2^T+b2); pooledsum -> mean
__global__ __launch_bounds__(512) void k_gate(const float* __restrict__ pooledsum,
                                              const float* __restrict__ w1,
                                              const float* __restrict__ b1,
                                              const float* __restrict__ w2,
                                              const float* __restrict__ b2,
                                              float* __restrict__ gamma) {
    __shared__ float hsh[NB][16];
    const int t = threadIdx.x;
    constexpr float inv = 1.f / (float)NHW;
    if (t < NB * 16) {
        const int b = t / 16, j = t % 16;
        float s = b1[j];
        for (int d = 0; d < NCR; ++d)
            s = fmaf(pooledsum[b * NCR + d] * inv, w1[j * NCR + d], s);
        hsh[b][j] = fmaxf(s, 0.f);
    }
    __syncthreads();
    const int b = t / NCR, d = t % NCR;
    float s = b2[d];
#pragma unroll
    for (int j = 0; j < 16; ++j) s = fmaf(hsh[b][j], w2[d * 16 + j], s);
    gamma[t] = 1.f / (1.f + expf(-s));
}

// K3a: per (b, 32x8 tile): stencil on y0+y1 -> kappa -> logits -> m
__global__ __launch_bounds__(256) void k_logits(const float* __restrict__ y0,
                                                const float* __restrict__ y1,
                                                const float* __restrict__ gamma,
                                                const float* __restrict__ fw,
                                                float* __restrict__ m) {
    __shared__ float tile[TH + 2][TW + 2];           // 10 x 34
    __shared__ float coef[NCR];

    const int b = blockIdx.z;
    const int w0 = blockIdx.x * TW, h0 = blockIdx.y * TH;
    const int t = threadIdx.x;
    const int tx = t % TW, ty = t / TW;

    if (t < NCR) coef[t] = fw[t] + gamma[b * NCR + t] * fw[NCR + t];
    __syncthreads();

    const size_t yoff = (size_t)b * NCR * NHW;
    float logit = 0.f;

    for (int c = 0; c < NCR; ++c) {
        const float* y0c = y0 + yoff + (size_t)c * NHW;
        const float* y1c = y1 + yoff + (size_t)c * NHW;
        for (int i = t; i < (TH + 2) * (TW + 2); i += 256) {
            const int iy = i / (TW + 2), ix = i % (TW + 2);
            const int gh = h0 + iy - 1, gw = w0 + ix - 1;
            float v = 0.f;
            if (gh >= 0 && gh < NH && gw >= 0 && gw < NW) {
                const int idx = gh * NW + gw;
                v = y0c[idx] + y1c[idx];
            }
            tile[iy][ix] = v;
        }
        __syncthreads();

        const float a00 = tile[ty][tx],     a01 = tile[ty][tx + 1],     a02 = tile[ty][tx + 2];
        const float a10 = tile[ty + 1][tx], a11 = tile[ty + 1][tx + 1], a12 = tile[ty + 1][tx + 2];
        const float a20 = tile[ty + 2][tx], a21 = tile[ty + 2][tx + 1], a22 = tile[ty + 2][tx + 2];

        const float mu = (a00 + a01 + a02 + a10 + a11 + a12 + a20 + a21 + a22) * (1.f / 9.f);
        const float gx = (a00 - a02 + 2.f * (a10 - a12) + a20 - a22) * 0.125f;
        const float gy = (a00 + 2.f * a01 + a02 - a20 - 2.f * a21 - a22) * 0.125f;
        const float kappa = 1.f - fabsf(a11 - mu) / (fabsf(gx) + fabsf(gy) + KEPS);
        logit = fmaf(kappa, coef[c], logit);
        __syncthreads();
    }

    const float a = 1.f / (1.f + expf(-logit));
    m[(size_t)b * NHW + (h0 + ty) * NW + (w0 + tx)] = 1.f + a;
}

// K3b: pure stream out = x * m. Overwrites ALL of d_out (incl. y1 scratch).
__global__ __launch_bounds__(256) void k_mul(const float* __restrict__ x,
                                             const float* __restrict__ m,
                                             float* __restrict__ out) {
    const int b = blockIdx.z;
    const int c0 = blockIdx.y * 4;
    const int p = blockIdx.x * 1024 + threadIdx.x * 4;

    const float4 mv = *reinterpret_cast<const float4*>(m + (size_t)b * NHW + p);
    const size_t base = (size_t)b * NC * NHW + (size_t)c0 * NHW + p;
    const float* xp = x + base;
    float* op = out + base;

#pragma unroll
    for (int cc = 0; cc < 4; ++cc) {
        const float4 v = *reinterpret_cast<const float4*>(xp + (size_t)cc * NHW);
        float4 r;
        r.x = v.x * mv.x; r.y = v.y * mv.y; r.z = v.z * mv.z; r.w = v.w * mv.w;
        *reinterpret_cast<float4*>(op + (size_t)cc * NHW) = r;
    }
}

extern "C" void kernel_launch(void* const* d_in, const int* in_sizes, int n_in,
                              void* d_out, int out_size, void* d_ws, size_t ws_size,
                              hipStream_t stream) {
    const float* x  = (const float*)d_in[0];
    const float* rw = (const float*)d_in[1];
    const float* w1 = (const float*)d_in[2];
    const float* b1 = (const float*)d_in[3];
    const float* w2 = (const float*)d_in[4];
    const float* b2 = (const float*)d_in[5];
    const float* fw = (const float*)d_in[6];
    float* out = (float*)d_out;

    float* y0     = (float*)d_ws;                       // 13,107,200 floats
    float* pooled = y0 + (size_t)NB * NCR * NHW;        // 512 floats (sums)
    float* gamma  = pooled + NB * NCR;                  // 512 floats
    float* rwT    = gamma + NB * NCR;                   // 16384 floats
    float* m      = rwT + NC * NCR;                     // 204800 floats
    float* y1     = out;                                // d_out scratch

    k_tr<<<dim3(64), 256, 0, stream>>>(rw, rwT, pooled);
    k_reduce<<<dim3(NHW / 512, NB, 2), 256, 0, stream>>>(x, rwT, y0, y1, pooled);
    k_gate<<<dim3(1), 512, 0, stream>>>(pooled, w1, b1, w2, b2, gamma);
    k_logits<<<dim3(NW / TW, NH / TH, NB), 256, 0, stream>>>(y0, y1, gamma, fw, m);
    k_mul<<<dim3(NHW / 1024, NC / 4, NB), 256, 0, stream>>>(x, m, out);
}

// Round 17
// 283.828 us; speedup vs baseline: 1.4907x; 1.3019x over previous
//
#include <hip/hip_runtime.h>
#include <math.h>
#include <stdint.h>

constexpr int NB = 8;
constexpr int NC = 256;
constexpr int NCR = 64;
constexpr int NH = 160;
constexpr int NW = 160;
constexpr int NHW = NH * NW;           // 25600
constexpr float KEPS = 1e-4f;

constexpr int TW = 32;                 // tile width (k_logits)
constexpr int TH = 8;                  // tile height (k_logits)

typedef __attribute__((ext_vector_type(8))) short bf16x8;
typedef __attribute__((ext_vector_type(4))) float f32x4;

union FragU { uint32_t u[4]; bf16x8 v; };

// exact 3-way bf16 truncation split: x == h + m + l (24-bit mantissa = 3x8)
__device__ inline void split3(float x, uint32_t& hm, uint16_t& lo) {
    const uint32_t u = __float_as_uint(x);
    const uint32_t h = u & 0xffff0000u;
    const float r1 = x - __uint_as_float(h);
    const uint32_t mu = __float_as_uint(r1) & 0xffff0000u;
    const float r2 = r1 - __uint_as_float(mu);
    hm = (h >> 16) | mu;                         // low ushort = h, high = m
    lo = (uint16_t)(__float_as_uint(r2) >> 16);
}

// K0: split rw[d][c] -> whm (packed h|m bf16) + wl; zero pooledsum
__global__ __launch_bounds__(256) void k_tr(const float* __restrict__ rw,
                                            uint32_t* __restrict__ whm,
                                            uint16_t* __restrict__ wl,
                                            float* __restrict__ pooledsum) {
    const int i = blockIdx.x * 256 + threadIdx.x;    // d*256+c, d-major
    uint32_t hm; uint16_t lo;
    split3(rw[i], hm, lo);
    whm[i] = hm; wl[i] = lo;
    if (blockIdx.x == 0) {
        pooledsum[threadIdx.x] = 0.f;
        pooledsum[256 + threadIdx.x] = 0.f;
    }
}

#define PERM __builtin_amdgcn_perm
#define MFMA __builtin_amdgcn_mfma_f32_16x16x32_bf16

// build lo/hi bf16x8 fragments from 8 packed uint32 (2 uint4)
__device__ inline void unpack8(const uint4 q0, const uint4 q1, bf16x8& fh, bf16x8& fm) {
    FragU a, b;
    a.u[0] = PERM(q0.y, q0.x, 0x05040100u);
    a.u[1] = PERM(q0.w, q0.z, 0x05040100u);
    a.u[2] = PERM(q1.y, q1.x, 0x05040100u);
    a.u[3] = PERM(q1.w, q1.z, 0x05040100u);
    b.u[0] = PERM(q0.y, q0.x, 0x07060302u);
    b.u[1] = PERM(q0.w, q0.z, 0x07060302u);
    b.u[2] = PERM(q1.y, q1.x, 0x07060302u);
    b.u[3] = PERM(q1.w, q1.z, 0x07060302u);
    fh = a.v; fm = b.v;
}

// K1: y[b][d][p] = sum_c W[d][c] x[b][c][p] via MFMA 16x16x32 bf16,
// 3-way-split operands, 6 products (error ~2^-24 rel, fp32-noise level).
// Block = 256 px x all 64 d; wave w owns px-subtiles nt = w*4..w*4+3.
// Per K-step (32 c): stage x-tile to LDS (packed splits), 2 barriers.
__global__ __launch_bounds__(256, 1) void k_reduce(const float* __restrict__ x,
                                                   const uint32_t* __restrict__ whm,
                                                   const uint16_t* __restrict__ wl,
                                                   float* __restrict__ y,
                                                   float* __restrict__ pooledsum) {
    __shared__ uint32_t xs_hm[256 * 36];             // [px][32c + pad4]
    __shared__ uint16_t xs_l[256 * 40];              // [px][32c + pad8]

    const int t = threadIdx.x;
    const int l = t & 63;
    const int wv = __builtin_amdgcn_readfirstlane(t >> 6);   // 0..3
    const int b = blockIdx.y;
    const int P0 = blockIdx.x * 256;

    const int lrow = l & 15;                         // fragment row/col lane id
    const int lgrp = l >> 4;                         // k-group 0..3

    f32x4 acc[4][4];
    const f32x4 fzero = {0.f, 0.f, 0.f, 0.f};
#pragma unroll
    for (int mi = 0; mi < 4; ++mi)
#pragma unroll
        for (int ni = 0; ni < 4; ++ni) acc[mi][ni] = fzero;

    const float* xbase = x + (size_t)b * NC * NHW + P0 + t;  // staging: px = t

    for (int ks = 0; ks < 8; ++ks) {
        // ---- stage 32 channels x 256 px, split into (h|m) + l ----
        {
            const float* xc = xbase + (size_t)(ks * 32) * NHW;
#pragma unroll
            for (int g = 0; g < 8; ++g) {
                const float v0 = xc[(size_t)(4 * g + 0) * NHW];
                const float v1 = xc[(size_t)(4 * g + 1) * NHW];
                const float v2 = xc[(size_t)(4 * g + 2) * NHW];
                const float v3 = xc[(size_t)(4 * g + 3) * NHW];
                uint32_t h0, h1, h2, h3; uint16_t l0, l1, l2, l3;
                split3(v0, h0, l0); split3(v1, h1, l1);
                split3(v2, h2, l2); split3(v3, h3, l3);
                uint4 hq; hq.x = h0; hq.y = h1; hq.z = h2; hq.w = h3;
                *reinterpret_cast<uint4*>(&xs_hm[t * 36 + 4 * g]) = hq;
                uint2 lq; lq.x = (uint32_t)l0 | ((uint32_t)l1 << 16);
                lq.y = (uint32_t)l2 | ((uint32_t)l3 << 16);
                *reinterpret_cast<uint2*>(&xs_l[t * 40 + 4 * g]) = lq;
            }
        }
        __syncthreads();

        // ---- A fragments for this K-step (4 m-tiles), from global (L1/L2-hot)
        bf16x8 Ah[4], Am[4], Al[4];
#pragma unroll
        for (int mi = 0; mi < 4; ++mi) {
            const int d = mi * 16 + lrow;
            const int c0 = ks * 32 + lgrp * 8;
            const uint4 q0 = *reinterpret_cast<const uint4*>(whm + d * 256 + c0);
            const uint4 q1 = *reinterpret_cast<const uint4*>(whm + d * 256 + c0 + 4);
            unpack8(q0, q1, Ah[mi], Am[mi]);
            Al[mi] = *reinterpret_cast<const bf16x8*>(wl + d * 256 + c0);
        }

        // ---- consume: 4 px-subtiles x 4 m-tiles x 6 products ----
#pragma unroll
        for (int ni = 0; ni < 4; ++ni) {
            const int row = (wv * 4 + ni) * 16 + lrow;
            const uint4 p0 = *reinterpret_cast<const uint4*>(&xs_hm[row * 36 + lgrp * 8]);
            const uint4 p1 = *reinterpret_cast<const uint4*>(&xs_hm[row * 36 + lgrp * 8 + 4]);
            bf16x8 Bh, Bm;
            unpack8(p0, p1, Bh, Bm);
            const bf16x8 Bl = *reinterpret_cast<const bf16x8*>(&xs_l[row * 40 + lgrp * 8]);
#pragma unroll
            for (int mi = 0; mi < 4; ++mi) {
                acc[mi][ni] = MFMA(Ah[mi], Bh, acc[mi][ni], 0, 0, 0);
                acc[mi][ni] = MFMA(Ah[mi], Bm, acc[mi][ni], 0, 0, 0);
                acc[mi][ni] = MFMA(Am[mi], Bh, acc[mi][ni], 0, 0, 0);
                acc[mi][ni] = MFMA(Ah[mi], Bl, acc[mi][ni], 0, 0, 0);
                acc[mi][ni] = MFMA(Am[mi], Bm, acc[mi][ni], 0, 0, 0);
                acc[mi][ni] = MFMA(Al[mi], Bh, acc[mi][ni], 0, 0, 0);
            }
        }
        __syncthreads();
    }

    // ---- store y: D layout col=lane&15 (px), row=(lane>>4)*4+reg (d) ----
    float* yb = y + (size_t)b * NCR * NHW;
#pragma unroll
    for (int mi = 0; mi < 4; ++mi)
#pragma unroll
        for (int ni = 0; ni < 4; ++ni) {
            const int px = P0 + (wv * 4 + ni) * 16 + lrow;
#pragma unroll
            for (int r = 0; r < 4; ++r) {
                const int d = mi * 16 + lgrp * 4 + r;
                yb[(size_t)d * NHW + px] = acc[mi][ni][r];
            }
        }

    // ---- pooled partial sums ----
    float* ps = pooledsum + b * NCR;
#pragma unroll
    for (int mi = 0; mi < 4; ++mi)
#pragma unroll
        for (int r = 0; r < 4; ++r) {
            float s = acc[mi][0][r] + acc[mi][1][r] + acc[mi][2][r] + acc[mi][3][r];
            s += __shfl_xor(s, 1, 64);
            s += __shfl_xor(s, 2, 64);
            s += __shfl_xor(s, 4, 64);
            s += __shfl_xor(s, 8, 64);
            if (lrow == 0) atomicAdd(&ps[mi * 16 + lgrp * 4 + r], s);
        }
}

// K2: gamma[b,d] = sigmoid(relu(mean@w1^T+b1)@w2^T+b2); pooledsum -> mean
__global__ __launch_bounds__(512) void k_gate(const float* __restrict__ pooledsum,
                                              const float* __restrict__ w1,
                                              const float* __restrict__ b1,
                                              const float* __restrict__ w2,
                                              const float* __restrict__ b2,
                                              float* __restrict__ gamma) {
    __shared__ float hsh[NB][16];
    const int t = threadIdx.x;
    constexpr float inv = 1.f / (float)NHW;
    if (t < NB * 16) {
        const int b = t / 16, j = t % 16;
        float s = b1[j];
        for (int d = 0; d < NCR; ++d)
            s = fmaf(pooledsum[b * NCR + d] * inv, w1[j * NCR + d], s);
        hsh[b][j] = fmaxf(s, 0.f);
    }
    __syncthreads();
    const int b = t / NCR, d = t % NCR;
    float s = b2[d];
#pragma unroll
    for (int j = 0; j < 16; ++j) s = fmaf(hsh[b][j], w2[d * 16 + j], s);
    gamma[t] = 1.f / (1.f + expf(-s));
}

// K3a: per (b, 32x8 tile): stencil on y -> kappa -> logits -> m = 1+sigmoid
__global__ __launch_bounds__(256) void k_logits(const float* __restrict__ y,
                                                const float* __restrict__ gamma,
                                                const float* __restrict__ fw,
                                                float* __restrict__ m) {
    __shared__ float tile[TH + 2][TW + 2];           // 10 x 34
    __shared__ float coef[NCR];

    const int b = blockIdx.z;
    const int w0 = blockIdx.x * TW, h0 = blockIdx.y * TH;
    const int t = threadIdx.x;
    const int tx = t % TW, ty = t / TW;

    if (t < NCR) coef[t] = fw[t] + gamma[b * NCR + t] * fw[NCR + t];
    __syncthreads();

    const float* yb = y + (size_t)b * NCR * NHW;
    float logit = 0.f;

    for (int c = 0; c < NCR; ++c) {
        const float* yc = yb + (size_t)c * NHW;
        for (int i = t; i < (TH + 2) * (TW + 2); i += 256) {
            const int iy = i / (TW + 2), ix = i % (TW + 2);
            const int gh = h0 + iy - 1, gw = w0 + ix - 1;
            float v = 0.f;
            if (gh >= 0 && gh < NH && gw >= 0 && gw < NW) v = yc[gh * NW + gw];
            tile[iy][ix] = v;
        }
        __syncthreads();

        const float a00 = tile[ty][tx],     a01 = tile[ty][tx + 1],     a02 = tile[ty][tx + 2];
        const float a10 = tile[ty + 1][tx], a11 = tile[ty + 1][tx + 1], a12 = tile[ty + 1][tx + 2];
        const float a20 = tile[ty + 2][tx], a21 = tile[ty + 2][tx + 1], a22 = tile[ty + 2][tx + 2];

        const float mu = (a00 + a01 + a02 + a10 + a11 + a12 + a20 + a21 + a22) * (1.f / 9.f);
        const float gx = (a00 - a02 + 2.f * (a10 - a12) + a20 - a22) * 0.125f;
        const float gy = (a00 + 2.f * a01 + a02 - a20 - 2.f * a21 - a22) * 0.125f;
        const float kappa = 1.f - fabsf(a11 - mu) / (fabsf(gx) + fabsf(gy) + KEPS);
        logit = fmaf(kappa, coef[c], logit);
        __syncthreads();
    }

    const float a = 1.f / (1.f + expf(-logit));
    m[(size_t)b * NHW + (h0 + ty) * NW + (w0 + tx)] = 1.f + a;
}

// K3b: pure stream out = x * m. Block: 256 thr over 1024 px; 4 channels each.
__global__ __launch_bounds__(256) void k_mul(const float* __restrict__ x,
                                             const float* __restrict__ m,
                                             float* __restrict__ out) {
    const int b = blockIdx.z;
    const int c0 = blockIdx.y * 4;
    const int p = blockIdx.x * 1024 + threadIdx.x * 4;

    const float4 mv = *reinterpret_cast<const float4*>(m + (size_t)b * NHW + p);
    const size_t base = (size_t)b * NC * NHW + (size_t)c0 * NHW + p;
    const float* xp = x + base;
    float* op = out + base;

#pragma unroll
    for (int cc = 0; cc < 4; ++cc) {
        const float4 v = *reinterpret_cast<const float4*>(xp + (size_t)cc * NHW);
        float4 r;
        r.x = v.x * mv.x; r.y = v.y * mv.y; r.z = v.z * mv.z; r.w = v.w * mv.w;
        *reinterpret_cast<float4*>(op + (size_t)cc * NHW) = r;
    }
}

extern "C" void kernel_launch(void* const* d_in, const int* in_sizes, int n_in,
                              void* d_out, int out_size, void* d_ws, size_t ws_size,
                              hipStream_t stream) {
    const float* x  = (const float*)d_in[0];
    const float* rw = (const float*)d_in[1];
    const float* w1 = (const float*)d_in[2];
    const float* b1 = (const float*)d_in[3];
    const float* w2 = (const float*)d_in[4];
    const float* b2 = (const float*)d_in[5];
    const float* fw = (const float*)d_in[6];
    float* out = (float*)d_out;

    float* y       = (float*)d_ws;                      // 13,107,200 floats
    float* pooled  = y + (size_t)NB * NCR * NHW;        // 512
    float* gamma   = pooled + NB * NCR;                 // 512
    float* m       = gamma + NB * NCR;                  // 204800
    uint32_t* whm  = (uint32_t*)(m + (size_t)NB * NHW); // 16384 u32
    uint16_t* wl   = (uint16_t*)(whm + NCR * NC);       // 16384 u16

    k_tr<<<dim3(64), 256, 0, stream>>>(rw, whm, wl, pooled);
    k_reduce<<<dim3(NHW / 256, NB), 256, 0, stream>>>(x, whm, wl, y, pooled);
    k_gate<<<dim3(1), 512, 0, stream>>>(pooled, w1, b1, w2, b2, gamma);
    k_logits<<<dim3(NW / TW, NH / TH, NB), 256, 0, stream>>>(y, gamma, fw, m);
    k_mul<<<dim3(NHW / 1024, NC / 4, NB), 256, 0, stream>>>(x, m, out);
}

// Round 18
// 276.323 us; speedup vs baseline: 1.5312x; 1.0272x over previous
//
#include <hip/hip_runtime.h>
#include <math.h>
#include <stdint.h>

constexpr int NB = 8;
constexpr int NC = 256;
constexpr int NCR = 64;
constexpr int NH = 160;
constexpr int NW = 160;
constexpr int NHW = NH * NW;           // 25600
constexpr float KEPS = 1e-4f;

constexpr int TW = 32;                 // tile width (k_logits)
constexpr int TH = 8;                  // tile height (k_logits)

typedef __attribute__((ext_vector_type(8))) short bf16x8;
typedef __attribute__((ext_vector_type(4))) float f32x4;

union FragU { uint32_t u[4]; bf16x8 v; };

// exact 3-way bf16 truncation split: x == h + m + l (24-bit mantissa = 3x8)
__device__ inline void split3(float x, uint32_t& hm, uint16_t& lo) {
    const uint32_t u = __float_as_uint(x);
    const uint32_t h = u & 0xffff0000u;
    const float r1 = x - __uint_as_float(h);
    const uint32_t mu = __float_as_uint(r1) & 0xffff0000u;
    const float r2 = r1 - __uint_as_float(mu);
    hm = (h >> 16) | mu;                         // low ushort = h, high = m
    lo = (uint16_t)(__float_as_uint(r2) >> 16);
}

// K0: split rw[d][c] -> whm (packed h|m bf16) + wl; zero pooledsum
__global__ __launch_bounds__(256) void k_tr(const float* __restrict__ rw,
                                            uint32_t* __restrict__ whm,
                                            uint16_t* __restrict__ wl,
                                            float* __restrict__ pooledsum) {
    const int i = blockIdx.x * 256 + threadIdx.x;    // d*256+c, d-major
    uint32_t hm; uint16_t lo;
    split3(rw[i], hm, lo);
    whm[i] = hm; wl[i] = lo;
    if (blockIdx.x == 0) {
        pooledsum[threadIdx.x] = 0.f;
        pooledsum[256 + threadIdx.x] = 0.f;
    }
}

#define PERM __builtin_amdgcn_perm
#define MFMA __builtin_amdgcn_mfma_f32_16x16x32_bf16

// build h/m bf16x8 fragments from 8 packed (h|m) uint32
__device__ inline void unpack8(const uint4 q0, const uint4 q1, bf16x8& fh, bf16x8& fm) {
    FragU a, b;
    a.u[0] = PERM(q0.y, q0.x, 0x05040100u);
    a.u[1] = PERM(q0.w, q0.z, 0x05040100u);
    a.u[2] = PERM(q1.y, q1.x, 0x05040100u);
    a.u[3] = PERM(q1.w, q1.z, 0x05040100u);
    b.u[0] = PERM(q0.y, q0.x, 0x07060302u);
    b.u[1] = PERM(q0.w, q0.z, 0x07060302u);
    b.u[2] = PERM(q1.y, q1.x, 0x07060302u);
    b.u[3] = PERM(q1.w, q1.z, 0x07060302u);
    fh = a.v; fm = b.v;
}

// split 8 raw fp32 into Bh/Bm/Bl bf16x8 fragments (split-on-read; ~44 VALU)
__device__ inline void buildB(const float4 a, const float4 b,
                              bf16x8& Bh, bf16x8& Bm, bf16x8& Bl) {
    FragU H, M, L;
    const float xv[8] = {a.x, a.y, a.z, a.w, b.x, b.y, b.z, b.w};
#pragma unroll
    for (int j = 0; j < 4; ++j) {
        const uint32_t u0 = __float_as_uint(xv[2 * j]);
        const uint32_t u1 = __float_as_uint(xv[2 * j + 1]);
        H.u[j] = PERM(u1, u0, 0x07060302u);
        const float r0 = xv[2 * j]     - __uint_as_float(u0 & 0xffff0000u);
        const float r1 = xv[2 * j + 1] - __uint_as_float(u1 & 0xffff0000u);
        const uint32_t v0 = __float_as_uint(r0);
        const uint32_t v1 = __float_as_uint(r1);
        M.u[j] = PERM(v1, v0, 0x07060302u);
        const float s0 = r0 - __uint_as_float(v0 & 0xffff0000u);
        const float s1 = r1 - __uint_as_float(v1 & 0xffff0000u);
        L.u[j] = PERM(__float_as_uint(s1), __float_as_uint(s0), 0x07060302u);
    }
    Bh = H.v; Bm = M.v; Bl = L.v;
}

// K1: y = W x via MFMA 16x16x32 bf16, 3-way split, 6 products (exact to
// ~2^-24 rel; R16 measured absmax == fp32's). Changes vs R16:
//  - x staged RAW fp32 (36 KB LDS, was 57) -> 4 blocks/CU by LDS; split
//    moved to read side (perm-packed, overlaps MFMA pipe across waves)
//  - A-frag global loads hoisted ABOVE staging -> L2 latency hidden
__global__ __launch_bounds__(256, 1) void k_reduce(const float* __restrict__ x,
                                                   const uint32_t* __restrict__ whm,
                                                   const uint16_t* __restrict__ wl,
                                                   float* __restrict__ y,
                                                   float* __restrict__ pooledsum) {
    __shared__ float xs[256 * 36];                   // [px][32c + pad4] = 36864 B

    const int t = threadIdx.x;
    const int l = t & 63;
    const int wv = __builtin_amdgcn_readfirstlane(t >> 6);   // 0..3
    const int b = blockIdx.y;
    const int P0 = blockIdx.x * 256;

    const int lrow = l & 15;                         // fragment row/col lane id
    const int lgrp = l >> 4;                         // k-group 0..3

    f32x4 acc[4][4];
    const f32x4 fzero = {0.f, 0.f, 0.f, 0.f};
#pragma unroll
    for (int mi = 0; mi < 4; ++mi)
#pragma unroll
        for (int ni = 0; ni < 4; ++ni) acc[mi][ni] = fzero;

    const float* xbase = x + (size_t)b * NC * NHW + P0 + t;  // staging: px = t

    for (int ks = 0; ks < 8; ++ks) {
        // ---- A-frag loads FIRST (independent of LDS; latency hides under
        //      the staging loads below) ----
        uint4 q0[4], q1[4];
        bf16x8 Alf[4];
#pragma unroll
        for (int mi = 0; mi < 4; ++mi) {
            const int d = mi * 16 + lrow;
            const int c0 = ks * 32 + lgrp * 8;
            q0[mi] = *reinterpret_cast<const uint4*>(whm + d * 256 + c0);
            q1[mi] = *reinterpret_cast<const uint4*>(whm + d * 256 + c0 + 4);
            Alf[mi] = *reinterpret_cast<const bf16x8*>(wl + d * 256 + c0);
        }

        // ---- stage 32 channels x 256 px raw fp32 ----
        {
            const float* xc = xbase + (size_t)(ks * 32) * NHW;
#pragma unroll
            for (int g = 0; g < 8; ++g) {
                float4 v;
                v.x = xc[(size_t)(4 * g + 0) * NHW];
                v.y = xc[(size_t)(4 * g + 1) * NHW];
                v.z = xc[(size_t)(4 * g + 2) * NHW];
                v.w = xc[(size_t)(4 * g + 3) * NHW];
                *reinterpret_cast<float4*>(&xs[t * 36 + 4 * g]) = v;
            }
        }
        __syncthreads();

        bf16x8 Ah[4], Am[4];
#pragma unroll
        for (int mi = 0; mi < 4; ++mi) unpack8(q0[mi], q1[mi], Ah[mi], Am[mi]);

        // ---- consume: 4 px-subtiles x 4 m-tiles x 6 products ----
#pragma unroll
        for (int ni = 0; ni < 4; ++ni) {
            const int row = (wv * 4 + ni) * 16 + lrow;
            const float4 xa = *reinterpret_cast<const float4*>(&xs[row * 36 + lgrp * 8]);
            const float4 xb2 = *reinterpret_cast<const float4*>(&xs[row * 36 + lgrp * 8 + 4]);
            bf16x8 Bh, Bm, Bl;
            buildB(xa, xb2, Bh, Bm, Bl);
#pragma unroll
            for (int mi = 0; mi < 4; ++mi) {
                acc[mi][ni] = MFMA(Ah[mi], Bh, acc[mi][ni], 0, 0, 0);
                acc[mi][ni] = MFMA(Ah[mi], Bm, acc[mi][ni], 0, 0, 0);
                acc[mi][ni] = MFMA(Am[mi], Bh, acc[mi][ni], 0, 0, 0);
                acc[mi][ni] = MFMA(Ah[mi], Bl, acc[mi][ni], 0, 0, 0);
                acc[mi][ni] = MFMA(Am[mi], Bm, acc[mi][ni], 0, 0, 0);
                acc[mi][ni] = MFMA(Alf[mi], Bh, acc[mi][ni], 0, 0, 0);
            }
        }
        __syncthreads();
    }

    // ---- store y: D layout col=lane&15 (px), row=(lane>>4)*4+reg (d) ----
    float* yb = y + (size_t)b * NCR * NHW;
#pragma unroll
    for (int mi = 0; mi < 4; ++mi)
#pragma unroll
        for (int ni = 0; ni < 4; ++ni) {
            const int px = P0 + (wv * 4 + ni) * 16 + lrow;
#pragma unroll
            for (int r = 0; r < 4; ++r) {
                const int d = mi * 16 + lgrp * 4 + r;
                yb[(size_t)d * NHW + px] = acc[mi][ni][r];
            }
        }

    // ---- pooled partial sums ----
    float* ps = pooledsum + b * NCR;
#pragma unroll
    for (int mi = 0; mi < 4; ++mi)
#pragma unroll
        for (int r = 0; r < 4; ++r) {
            float s = acc[mi][0][r] + acc[mi][1][r] + acc[mi][2][r] + acc[mi][3][r];
            s += __shfl_xor(s, 1, 64);
            s += __shfl_xor(s, 2, 64);
            s += __shfl_xor(s, 4, 64);
            s += __shfl_xor(s, 8, 64);
            if (lrow == 0) atomicAdd(&ps[mi * 16 + lgrp * 4 + r], s);
        }
}

// K2: gamma[b,d] = sigmoid(relu(mean@w1^T+b1)@w2^T+b2); pooledsum -> mean
__global__ __launch_bounds__(512) void k_gate(const float* __restrict__ pooledsum,
                                              const float* __restrict__ w1,
                                              const float* __restrict__ b1,
                                              const float* __restrict__ w2,
                                              const float* __restrict__ b2,
                                              float* __restrict__ gamma) {
    __shared__ float hsh[NB][16];
    const int t = threadIdx.x;
    constexpr float inv = 1.f / (float)NHW;
    if (t < NB * 16) {
        const int b = t / 16, j = t % 16;
        float s = b1[j];
        for (int d = 0; d < NCR; ++d)
            s = fmaf(pooledsum[b * NCR + d] * inv, w1[j * NCR + d], s);
        hsh[b][j] = fmaxf(s, 0.f);
    }
    __syncthreads();
    const int b = t / NCR, d = t % NCR;
    float s = b2[d];
#pragma unroll
    for (int j = 0; j < 16; ++j) s = fmaf(hsh[b][j], w2[d * 16 + j], s);
    gamma[t] = 1.f / (1.f + expf(-s));
}

// K3a: per (b, 32x8 tile): stencil on y -> kappa -> logits -> m = 1+sigmoid
__global__ __launch_bounds__(256) void k_logits(const float* __restrict__ y,
                                                const float* __restrict__ gamma,
                                                const float* __restrict__ fw,
                                                float* __restrict__ m) {
    __shared__ float tile[TH + 2][TW + 2];           // 10 x 34
    __shared__ float coef[NCR];

    const int b = blockIdx.z;
    const int w0 = blockIdx.x * TW, h0 = blockIdx.y * TH;
    const int t = threadIdx.x;
    const int tx = t % TW, ty = t / TW;

    if (t < NCR) coef[t] = fw[t] + gamma[b * NCR + t] * fw[NCR + t];
    __syncthreads();

    const float* yb = y + (size_t)b * NCR * NHW;
    float logit = 0.f;

    for (int c = 0; c < NCR; ++c) {
        const float* yc = yb + (size_t)c * NHW;
        for (int i = t; i < (TH + 2) * (TW + 2); i += 256) {
            const int iy = i / (TW + 2), ix = i % (TW + 2);
            const int gh = h0 + iy - 1, gw = w0 + ix - 1;
            float v = 0.f;
            if (gh >= 0 && gh < NH && gw >= 0 && gw < NW) v = yc[gh * NW + gw];
            tile[iy][ix] = v;
        }
        __syncthreads();

        const float a00 = tile[ty][tx],     a01 = tile[ty][tx + 1],     a02 = tile[ty][tx + 2];
        const float a10 = tile[ty + 1][tx], a11 = tile[ty + 1][tx + 1], a12 = tile[ty + 1][tx + 2];
        const float a20 = tile[ty + 2][tx], a21 = tile[ty + 2][tx + 1], a22 = tile[ty + 2][tx + 2];

        const float mu = (a00 + a01 + a02 + a10 + a11 + a12 + a20 + a21 + a22) * (1.f / 9.f);
        const float gx = (a00 - a02 + 2.f * (a10 - a12) + a20 - a22) * 0.125f;
        const float gy = (a00 + 2.f * a01 + a02 - a20 - 2.f * a21 - a22) * 0.125f;
        const float kappa = 1.f - fabsf(a11 - mu) / (fabsf(gx) + fabsf(gy) + KEPS);
        logit = fmaf(kappa, coef[c], logit);
        __syncthreads();
    }

    const float a = 1.f / (1.f + expf(-logit));
    m[(size_t)b * NHW + (h0 + ty) * NW + (w0 + tx)] = 1.f + a;
}

// K3b: pure stream out = x * m. Block: 256 thr over 1024 px; 4 channels each.
__global__ __launch_bounds__(256) void k_mul(const float* __restrict__ x,
                                             const float* __restrict__ m,
                                             float* __restrict__ out) {
    const int b = blockIdx.z;
    const int c0 = blockIdx.y * 4;
    const int p = blockIdx.x * 1024 + threadIdx.x * 4;

    const float4 mv = *reinterpret_cast<const float4*>(m + (size_t)b * NHW + p);
    const size_t base = (size_t)b * NC * NHW + (size_t)c0 * NHW + p;
    const float* xp = x + base;
    float* op = out + base;

#pragma unroll
    for (int cc = 0; cc < 4; ++cc) {
        const float4 v = *reinterpret_cast<const float4*>(xp + (size_t)cc * NHW);
        float4 r;
        r.x = v.x * mv.x; r.y = v.y * mv.y; r.z = v.z * mv.z; r.w = v.w * mv.w;
        *reinterpret_cast<float4*>(op + (size_t)cc * NHW) = r;
    }
}

extern "C" void kernel_launch(void* const* d_in, const int* in_sizes, int n_in,
                              void* d_out, int out_size, void* d_ws, size_t ws_size,
                              hipStream_t stream) {
    const float* x  = (const float*)d_in[0];
    const float* rw = (const float*)d_in[1];
    const float* w1 = (const float*)d_in[2];
    const float* b1 = (const float*)d_in[3];
    const float* w2 = (const float*)d_in[4];
    const float* b2 = (const float*)d_in[5];
    const float* fw = (const float*)d_in[6];
    float* out = (float*)d_out;

    float* y       = (float*)d_ws;                      // 13,107,200 floats
    float* pooled  = y + (size_t)NB * NCR * NHW;        // 512
    float* gamma   = pooled + NB * NCR;                 // 512
    float* m       = gamma + NB * NCR;                  // 204800
    uint32_t* whm  = (uint32_t*)(m + (size_t)NB * NHW); // 16384 u32
    uint16_t* wl   = (uint16_t*)(whm + NCR * NC);       // 16384 u16

    k_tr<<<dim3(64), 256, 0, stream>>>(rw, whm, wl, pooled);
    k_reduce<<<dim3(NHW / 256, NB), 256, 0, stream>>>(x, whm, wl, y, pooled);
    k_gate<<<dim3(1), 512, 0, stream>>>(pooled, w1, b1, w2, b2, gamma);
    k_logits<<<dim3(NW / TW, NH / TH, NB), 256, 0, stream>>>(y, gamma, fw, m);
    k_mul<<<dim3(NHW / 1024, NC / 4, NB), 256, 0, stream>>>(x, m, out);
}

// Round 19
// 275.455 us; speedup vs baseline: 1.5360x; 1.0031x over previous
//
#include <hip/hip_runtime.h>
#include <math.h>
#include <stdint.h>

constexpr int NB = 8;
constexpr int NC = 256;
constexpr int NCR = 64;
constexpr int NH = 160;
constexpr int NW = 160;
constexpr int NHW = NH * NW;           // 25600
constexpr float KEPS = 1e-4f;

constexpr int TW = 32;                 // tile width (k_logits)
constexpr int TH = 8;                  // tile height (k_logits)

typedef __attribute__((ext_vector_type(8))) short bf16x8;
typedef __attribute__((ext_vector_type(4))) float f32x4;

union FragU { uint32_t u[4]; bf16x8 v; };

// exact 3-way bf16 truncation split: x == h + m + l (24-bit mantissa = 3x8)
__device__ inline void split3(float x, uint32_t& hm, uint16_t& lo) {
    const uint32_t u = __float_as_uint(x);
    const uint32_t h = u & 0xffff0000u;
    const float r1 = x - __uint_as_float(h);
    const uint32_t mu = __float_as_uint(r1) & 0xffff0000u;
    const float r2 = r1 - __uint_as_float(mu);
    hm = (h >> 16) | mu;                         // low ushort = h, high = m
    lo = (uint16_t)(__float_as_uint(r2) >> 16);
}

// K0: split rw[d][c] -> whm (packed h|m bf16) + wl; zero pooledsum
__global__ __launch_bounds__(256) void k_tr(const float* __restrict__ rw,
                                            uint32_t* __restrict__ whm,
                                            uint16_t* __restrict__ wl,
                                            float* __restrict__ pooledsum) {
    const int i = blockIdx.x * 256 + threadIdx.x;    // d*256+c, d-major
    uint32_t hm; uint16_t lo;
    split3(rw[i], hm, lo);
    whm[i] = hm; wl[i] = lo;
    if (blockIdx.x == 0) {
        pooledsum[threadIdx.x] = 0.f;
        pooledsum[256 + threadIdx.x] = 0.f;
    }
}

#define PERM __builtin_amdgcn_perm
#define MFMA __builtin_amdgcn_mfma_f32_16x16x32_bf16

typedef __attribute__((address_space(1))) const void GV;
typedef __attribute__((address_space(3))) void LV;

// build h/m bf16x8 fragments from 8 packed (h|m) uint32
__device__ inline void unpack8(const uint4 q0, const uint4 q1, bf16x8& fh, bf16x8& fm) {
    FragU a, b;
    a.u[0] = PERM(q0.y, q0.x, 0x05040100u);
    a.u[1] = PERM(q0.w, q0.z, 0x05040100u);
    a.u[2] = PERM(q1.y, q1.x, 0x05040100u);
    a.u[3] = PERM(q1.w, q1.z, 0x05040100u);
    b.u[0] = PERM(q0.y, q0.x, 0x07060302u);
    b.u[1] = PERM(q0.w, q0.z, 0x07060302u);
    b.u[2] = PERM(q1.y, q1.x, 0x07060302u);
    b.u[3] = PERM(q1.w, q1.z, 0x07060302u);
    fh = a.v; fm = b.v;
}

// split 8 raw fp32 into Bh/Bm/Bl bf16x8 fragments (split-on-read)
__device__ inline void buildB8(const float* xv, bf16x8& Bh, bf16x8& Bm, bf16x8& Bl) {
    FragU H, M, L;
#pragma unroll
    for (int j = 0; j < 4; ++j) {
        const uint32_t u0 = __float_as_uint(xv[2 * j]);
        const uint32_t u1 = __float_as_uint(xv[2 * j + 1]);
        H.u[j] = PERM(u1, u0, 0x07060302u);
        const float r0 = xv[2 * j]     - __uint_as_float(u0 & 0xffff0000u);
        const float r1 = xv[2 * j + 1] - __uint_as_float(u1 & 0xffff0000u);
        const uint32_t v0 = __float_as_uint(r0);
        const uint32_t v1 = __float_as_uint(r1);
        M.u[j] = PERM(v1, v0, 0x07060302u);
        const float s0 = r0 - __uint_as_float(v0 & 0xffff0000u);
        const float s1 = r1 - __uint_as_float(v1 & 0xffff0000u);
        L.u[j] = PERM(__float_as_uint(s1), __float_as_uint(s0), 0x07060302u);
    }
    Bh = H.v; Bm = M.v; Bl = L.v;
}

constexpr int XROW = 260;              // LDS row stride (floats), 16B-aligned

// K1: y = W x via MFMA 16x16x32 bf16, 3-way split, 6 products.
// Staging now ASYNC global_load_lds width-16: ONE instruction per channel
// (64 lanes x 16B = 1KB = 256px), channel-major LDS [c][px]. Replaces 32
// scalar strided global loads + 8 ds_writes per wave per K-step and all
// vmcnt-to-register stalls (loads drain at the barrier instead).
__global__ __launch_bounds__(256, 1) void k_reduce(const float* __restrict__ x,
                                                   const uint32_t* __restrict__ whm,
                                                   const uint16_t* __restrict__ wl,
                                                   float* __restrict__ y,
                                                   float* __restrict__ pooledsum) {
    __shared__ float xs[32 * XROW];                  // 33280 B

    const int t = threadIdx.x;
    const int l = t & 63;
    const int wv = __builtin_amdgcn_readfirstlane(t >> 6);   // 0..3
    const int b = blockIdx.y;
    const int P0 = blockIdx.x * 256;

    const int lrow = l & 15;                         // fragment row/col lane id
    const int lgrp = l >> 4;                         // k-group 0..3

    f32x4 acc[4][4];
    const f32x4 fzero = {0.f, 0.f, 0.f, 0.f};
#pragma unroll
    for (int mi = 0; mi < 4; ++mi)
#pragma unroll
        for (int ni = 0; ni < 4; ++ni) acc[mi][ni] = fzero;

    const float* xbase = x + (size_t)b * NC * NHW + P0;

    for (int ks = 0; ks < 8; ++ks) {
        // ---- async stage: this wave stages channels wv*8 .. wv*8+7 ----
        {
            const float* xc = xbase + (size_t)(ks * 32) * NHW;
#pragma unroll
            for (int j = 0; j < 8; ++j) {
                const int c = wv * 8 + j;
                const float* gp = xc + (size_t)c * NHW + 4 * l;   // lane's 16B
                float* lp = &xs[c * XROW];                        // wave-uniform
                __builtin_amdgcn_global_load_lds((GV*)gp, (LV*)lp, 16, 0, 0);
            }
        }

        // ---- A-frag loads (VGPR; latency hides under the async stage) ----
        uint4 q0[4], q1[4];
        bf16x8 Alf[4];
#pragma unroll
        for (int mi = 0; mi < 4; ++mi) {
            const int d = mi * 16 + lrow;
            const int c0 = ks * 32 + lgrp * 8;
            q0[mi] = *reinterpret_cast<const uint4*>(whm + d * 256 + c0);
            q1[mi] = *reinterpret_cast<const uint4*>(whm + d * 256 + c0 + 4);
            Alf[mi] = *reinterpret_cast<const bf16x8*>(wl + d * 256 + c0);
        }

        __syncthreads();                             // drains vmcnt incl. LDS loads

        bf16x8 Ah[4], Am[4];
#pragma unroll
        for (int mi = 0; mi < 4; ++mi) unpack8(q0[mi], q1[mi], Ah[mi], Am[mi]);

        // ---- consume: 4 px-subtiles x 4 m-tiles x 6 products ----
#pragma unroll
        for (int ni = 0; ni < 4; ++ni) {
            const int row = (wv * 4 + ni) * 16 + lrow;
            float xv[8];
#pragma unroll
            for (int j = 0; j < 8; ++j)
                xv[j] = xs[(lgrp * 8 + j) * XROW + row];
            bf16x8 Bh, Bm, Bl;
            buildB8(xv, Bh, Bm, Bl);
#pragma unroll
            for (int mi = 0; mi < 4; ++mi) {
                acc[mi][ni] = MFMA(Ah[mi], Bh, acc[mi][ni], 0, 0, 0);
                acc[mi][ni] = MFMA(Ah[mi], Bm, acc[mi][ni], 0, 0, 0);
                acc[mi][ni] = MFMA(Am[mi], Bh, acc[mi][ni], 0, 0, 0);
                acc[mi][ni] = MFMA(Ah[mi], Bl, acc[mi][ni], 0, 0, 0);
                acc[mi][ni] = MFMA(Am[mi], Bm, acc[mi][ni], 0, 0, 0);
                acc[mi][ni] = MFMA(Alf[mi], Bh, acc[mi][ni], 0, 0, 0);
            }
        }
        __syncthreads();
    }

    // ---- store y: D layout col=lane&15 (px), row=(lane>>4)*4+reg (d) ----
    float* yb = y + (size_t)b * NCR * NHW;
#pragma unroll
    for (int mi = 0; mi < 4; ++mi)
#pragma unroll
        for (int ni = 0; ni < 4; ++ni) {
            const int px = P0 + (wv * 4 + ni) * 16 + lrow;
#pragma unroll
            for (int r = 0; r < 4; ++r) {
                const int d = mi * 16 + lgrp * 4 + r;
                yb[(size_t)d * NHW + px] = acc[mi][ni][r];
            }
        }

    // ---- pooled partial sums ----
    float* ps = pooledsum + b * NCR;
#pragma unroll
    for (int mi = 0; mi < 4; ++mi)
#pragma unroll
        for (int r = 0; r < 4; ++r) {
            float s = acc[mi][0][r] + acc[mi][1][r] + acc[mi][2][r] + acc[mi][3][r];
            s += __shfl_xor(s, 1, 64);
            s += __shfl_xor(s, 2, 64);
            s += __shfl_xor(s, 4, 64);
            s += __shfl_xor(s, 8, 64);
            if (lrow == 0) atomicAdd(&ps[mi * 16 + lgrp * 4 + r], s);
        }
}

// K2: gamma[b,d] = sigmoid(relu(mean@w1^T+b1)@w2^T+b2); pooledsum -> mean
__global__ __launch_bounds__(512) void k_gate(const float* __restrict__ pooledsum,
                                              const float* __restrict__ w1,
                                              const float* __restrict__ b1,
                                              const float* __restrict__ w2,
                                              const float* __restrict__ b2,
                                              float* __restrict__ gamma) {
    __shared__ float hsh[NB][16];
    const int t = threadIdx.x;
    constexpr float inv = 1.f / (float)NHW;
    if (t < NB * 16) {
        const int b = t / 16, j = t % 16;
        float s = b1[j];
        for (int d = 0; d < NCR; ++d)
            s = fmaf(pooledsum[b * NCR + d] * inv, w1[j * NCR + d], s);
        hsh[b][j] = fmaxf(s, 0.f);
    }
    __syncthreads();
    const int b = t / NCR, d = t % NCR;
    float s = b2[d];
#pragma unroll
    for (int j = 0; j < 16; ++j) s = fmaf(hsh[b][j], w2[d * 16 + j], s);
    gamma[t] = 1.f / (1.f + expf(-s));
}

// K3a: per (b, 32x8 tile): stencil on y -> kappa -> logits -> m = 1+sigmoid
__global__ __launch_bounds__(256) void k_logits(const float* __restrict__ y,
                                                const float* __restrict__ gamma,
                                                const float* __restrict__ fw,
                                                float* __restrict__ m) {
    __shared__ float tile[TH + 2][TW + 2];           // 10 x 34
    __shared__ float coef[NCR];

    const int b = blockIdx.z;
    const int w0 = blockIdx.x * TW, h0 = blockIdx.y * TH;
    const int t = threadIdx.x;
    const int tx = t % TW, ty = t / TW;

    if (t < NCR) coef[t] = fw[t] + gamma[b * NCR + t] * fw[NCR + t];
    __syncthreads();

    const float* yb = y + (size_t)b * NCR * NHW;
    float logit = 0.f;

    for (int c = 0; c < NCR; ++c) {
        const float* yc = yb + (size_t)c * NHW;
        for (int i = t; i < (TH + 2) * (TW + 2); i += 256) {
            const int iy = i / (TW + 2), ix = i % (TW + 2);
            const int gh = h0 + iy - 1, gw = w0 + ix - 1;
            float v = 0.f;
            if (gh >= 0 && gh < NH && gw >= 0 && gw < NW) v = yc[gh * NW + gw];
            tile[iy][ix] = v;
        }
        __syncthreads();

        const float a00 = tile[ty][tx],     a01 = tile[ty][tx + 1],     a02 = tile[ty][tx + 2];
        const float a10 = tile[ty + 1][tx], a11 = tile[ty + 1][tx + 1], a12 = tile[ty + 1][tx + 2];
        const float a20 = tile[ty + 2][tx], a21 = tile[ty + 2][tx + 1], a22 = tile[ty + 2][tx + 2];

        const float mu = (a00 + a01 + a02 + a10 + a11 + a12 + a20 + a21 + a22) * (1.f / 9.f);
        const float gx = (a00 - a02 + 2.f * (a10 - a12) + a20 - a22) * 0.125f;
        const float gy = (a00 + 2.f * a01 + a02 - a20 - 2.f * a21 - a22) * 0.125f;
        const float kappa = 1.f - fabsf(a11 - mu) / (fabsf(gx) + fabsf(gy) + KEPS);
        logit = fmaf(kappa, coef[c], logit);
        __syncthreads();
    }

    const float a = 1.f / (1.f + expf(-logit));
    m[(size_t)b * NHW + (h0 + ty) * NW + (w0 + tx)] = 1.f + a;
}

// K3b: pure stream out = x * m. Block: 256 thr over 1024 px; 4 channels each.
__global__ __launch_bounds__(256) void k_mul(const float* __restrict__ x,
                                             const float* __restrict__ m,
                                             float* __restrict__ out) {
    const int b = blockIdx.z;
    const int c0 = blockIdx.y * 4;
    const int p = blockIdx.x * 1024 + threadIdx.x * 4;

    const float4 mv = *reinterpret_cast<const float4*>(m + (size_t)b * NHW + p);
    const size_t base = (size_t)b * NC * NHW + (size_t)c0 * NHW + p;
    const float* xp = x + base;
    float* op = out + base;

#pragma unroll
    for (int cc = 0; cc < 4; ++cc) {
        const float4 v = *reinterpret_cast<const float4*>(xp + (size_t)cc * NHW);
        float4 r;
        r.x = v.x * mv.x; r.y = v.y * mv.y; r.z = v.z * mv.z; r.w = v.w * mv.w;
        *reinterpret_cast<float4*>(op + (size_t)cc * NHW) = r;
    }
}

extern "C" void kernel_launch(void* const* d_in, const int* in_sizes, int n_in,
                              void* d_out, int out_size, void* d_ws, size_t ws_size,
                              hipStream_t stream) {
    const float* x  = (const float*)d_in[0];
    const float* rw = (const float*)d_in[1];
    const float* w1 = (const float*)d_in[2];
    const float* b1 = (const float*)d_in[3];
    const float* w2 = (const float*)d_in[4];
    const float* b2 = (const float*)d_in[5];
    const float* fw = (const float*)d_in[6];
    float* out = (float*)d_out;

    float* y       = (float*)d_ws;                      // 13,107,200 floats
    float* pooled  = y + (size_t)NB * NCR * NHW;        // 512
    float* gamma   = pooled + NB * NCR;                 // 512
    float* m       = gamma + NB * NCR;                  // 204800
    uint32_t* whm  = (uint32_t*)(m + (size_t)NB * NHW); // 16384 u32
    uint16_t* wl   = (uint16_t*)(whm + NCR * NC);       // 16384 u16

    k_tr<<<dim3(64), 256, 0, stream>>>(rw, whm, wl, pooled);
    k_reduce<<<dim3(NHW / 256, NB), 256, 0, stream>>>(x, whm, wl, y, pooled);
    k_gate<<<dim3(1), 512, 0, stream>>>(pooled, w1, b1, w2, b2, gamma);
    k_logits<<<dim3(NW / TW, NH / TH, NB), 256, 0, stream>>>(y, gamma, fw, m);
    k_mul<<<dim3(NHW / 1024, NC / 4, NB), 256, 0, stream>>>(x, m, out);
}